// Round 12
// baseline (267.613 us; speedup 1.0000x reference)
//
#include <hip/hip_runtime.h>
#include <hip/hip_bf16.h>

#define NN 40000
#define NE 640000

typedef unsigned int u32;
typedef unsigned short u16;
typedef __attribute__((ext_vector_type(8))) short bf16x8;
typedef __attribute__((ext_vector_type(4))) float f32x4;

// ---------------- static device scratch (direct symbol use; no d_ws) -------
// h' matrices are stored as 8 COLUMN PANELS of [NN][16] bf16 (1.25MB each):
// panel p holds cols [p*16, p*16+16). Shard x (XCD x via blockIdx%8) gathers
// only from its panel -> per-XCD L2-resident working set.
__device__ float g_wf[512];                  // biases + Wout + bout (f32)
__device__ u16   g_wp[40960];                // bf16 W1/W2/W3 in MFMA B-fragment layout
__device__ int   g_cnt[NN];                  // zero at load; re-zeroed by aggsh1
__device__ int   g_cur[NN];                  // zero at load; re-zeroed by aggsh1
__device__ int   g_rowptr[NN + 1];
__device__ float g_dinv[NN];
__device__ int   g_csrc[NE];
__device__ int   g_bsum[64];
__device__ u16   g_ha[(size_t)NN * 128];     // panels: x input, then agg outputs
__device__ u16   g_hb[(size_t)NN * 128];     // panels: gemm1 out / gemm3 out
__device__ u16   g_hb2[(size_t)NN * 128];    // panels: gemm2 out

#define PANEL ((size_t)NN * 16)              // u16 elements per panel

// g_wf offsets
#define OFF_B1 0
#define OFF_B2 128
#define OFF_B3 256
#define OFF_WO 320
#define OFF_BO 448
// g_wp offsets
#define WP_W1 0
#define WP_W2 16384
#define WP_W3 32768

__device__ __forceinline__ float b2f(u16 v){ return __uint_as_float(((u32)v) << 16); }
__device__ __forceinline__ float blo(u32 u){ return __uint_as_float(u << 16); }
__device__ __forceinline__ float bhi(u32 u){ return __uint_as_float(u & 0xffff0000u); }
__device__ __forceinline__ u32 f2bf(float f){
  u32 u = __float_as_uint(f);
  return (u + 0x7fffu + ((u >> 16) & 1u)) >> 16;   // RNE
}
__device__ __forceinline__ int clampi(int v, int lo, int hi){ return v < lo ? lo : (v > hi ? hi : v); }
__device__ __forceinline__ u16 ldbf(const void* p, int idx, int f32){
  return f32 ? (u16)f2bf(((const float*)p)[idx]) : ((const u16*)p)[idx];
}
__device__ __forceinline__ float ldf(const void* p, int idx, int f32){
  return f32 ? ((const float*)p)[idx] : b2f(((const u16*)p)[idx]);
}

// ---- per-block dtype self-detection (64 fixed samples, wave ballot) ----
__device__ __forceinline__ int detect_xf32(const u16* __restrict__ xf){
  int i = ((int)threadIdx.x & 63) * 64;
  u16 v = xf[2 * i];
  int e = (v >> 7) & 0xff;
  int pass = (v == 0 || (e >= 100 && e <= 140)) ? 1 : 0;
  return (__popcll(__ballot(pass)) < 32) ? 1 : 0;        // few bf16-like -> f32
}
__device__ __forceinline__ int detect_estride(const int* __restrict__ ei){
  int i = ((int)threadIdx.x & 63) * 64;
  int pass = (ei[2 * i + 1] == 0) ? 1 : 0;               // int64 high words are 0
  return (__popcll(__ballot(pass)) >= 32) ? 2 : 1;
}

// ---- 1) fused preamble: cvt_x (to panels) + in-degree count | packw | table ----
__global__ __launch_bounds__(256) void k_prep(const void* xin, const int* __restrict__ ei,
                                              const void* w1, const void* b1,
                                              const void* w2, const void* b2, const void* w3,
                                              const void* b3, const void* wo, const void* bo){
  int xf32 = detect_xf32((const u16*)xin);
  int strd = detect_estride(ei);
  int T = (int)blockIdx.x * 256 + (int)threadIdx.x;
  if (T < 640000){
    // x convert: thread T handles node T>>4, cols (T&15)*8..+8
    uint4 o;
    if (xf32){
      const float4* p = (const float4*)xin + (size_t)T * 2;
      float4 a = p[0], b = p[1];
      o.x = f2bf(a.x) | (f2bf(a.y) << 16);
      o.y = f2bf(a.z) | (f2bf(a.w) << 16);
      o.z = f2bf(b.x) | (f2bf(b.y) << 16);
      o.w = f2bf(b.z) | (f2bf(b.w) << 16);
    } else {
      o = ((const uint4*)xin)[T];
    }
    // panel p = (T>>1)&7, within-panel u16 offset = node*16 + (T&1)*8
    int pnl = (T >> 1) & 7;
    ((uint4*)g_ha)[(size_t)pnl * 80000 + (size_t)(T >> 4) * 2 + (T & 1)] = o;
    int d = clampi(ei[(size_t)(NE + T) * strd], 0, NN - 1);
    atomicAdd(&g_cnt[d], 1);
  } else if (T < 680960){
    int local = T - 640000;
    int J, dstbase, l; const void* src;
    if (local < 16384){ J = 128; src = w1; dstbase = WP_W1; l = local; }
    else if (local < 32768){ J = 128; src = w2; dstbase = WP_W2; l = local - 16384; }
    else { J = 64; src = w3; dstbase = WP_W3; l = local - 32768; }
    int chunk = l >> 9, within = l & 511;
    int nbw = J / 16;
    int kb = chunk / nbw, nb = chunk % nbw;
    int lane = within >> 3, j = within & 7;
    int q = lane >> 4, n = lane & 15;
    int k = kb * 32 + q * 8 + j;
    int col = nb * 16 + n;
    g_wp[dstbase + l] = ldbf(src, k * J + col, xf32);
  } else if (T < 681410){
    int l = T - 680960;                      // 0..449
    if (l < 128)      g_wf[OFF_B1 + l] = ldf(b1, l, xf32);
    else if (l < 256) g_wf[OFF_B2 + l - 128] = ldf(b2, l - 128, xf32);
    else if (l < 320) g_wf[OFF_B3 + l - 256] = ldf(b3, l - 256, xf32);
    else if (l < 448) g_wf[OFF_WO + l - 320] = ldf(wo, l - 320, xf32);
    else              g_wf[OFF_BO + l - 448] = ldf(bo, l - 448, xf32);
  }
}

// ---- 2a) block-level scan (40 blocks x 1024): local exclusive + block sums ----
__global__ __launch_bounds__(1024) void k_scan1(){
  int t = (int)threadIdx.x;
  int b = (int)blockIdx.x;
  int i = b * 1024 + t;
  int v = (i < NN) ? g_cnt[i] : 0;
  int lane = t & 63, wv = t >> 6;
  int x = v;
#pragma unroll
  for (int ofs = 1; ofs < 64; ofs <<= 1){
    int y = __shfl_up(x, ofs, 64);
    if (lane >= ofs) x += y;
  }
  __shared__ int wsum[16];
  if (lane == 63) wsum[wv] = x;
  __syncthreads();
  if (t < 16){
    int s = wsum[t];
#pragma unroll
    for (int ofs = 1; ofs < 16; ofs <<= 1){
      int y = __shfl_up(s, ofs, 64);
      if (t >= ofs) s += y;
    }
    wsum[t] = s;
  }
  __syncthreads();
  int pre = (wv == 0) ? 0 : wsum[wv - 1];
  int incl = x + pre;
  if (i < NN){
    g_rowptr[i] = incl - v;
    g_dinv[i] = rsqrtf((float)(v + 1));
  }
  if (t == 1023) g_bsum[b] = incl;
}

// ---- 2b) add block offsets ----
__global__ __launch_bounds__(1024) void k_scan3(){
  __shared__ int pre;
  int t = (int)threadIdx.x;
  if (t < 64){
    int v = (t < 40) ? g_bsum[t] : 0;
    int s = v;
#pragma unroll
    for (int ofs = 1; ofs < 64; ofs <<= 1){
      int y = __shfl_up(s, ofs, 64);
      if (t >= ofs) s += y;
    }
    if (t == (int)blockIdx.x) pre = s - v;               // exclusive prefix for this block
    if (blockIdx.x == 0 && t == 39) g_rowptr[NN] = s;    // grand total
  }
  __syncthreads();
  int i = (int)blockIdx.x * 1024 + t;
  if (i < NN) g_rowptr[i] += pre;
}

// ---- shared GEMM body: [NN x 128] panels @ W[128 x JOUT] -> JOUT/16 panels ----
template<int JOUT>
__device__ __forceinline__ void gemm_body(int bid, int wpoff,
                                          const u16* __restrict__ apan,
                                          u16* __restrict__ dst){
  constexpr int NB = JOUT / 16;
  int tid = (int)threadIdx.x;
  int wave = tid >> 6, lane = tid & 63;
  int q = lane >> 4, n = lane & 15;
  int m0 = bid * 64 + wave * 16;
  f32x4 acc[NB];
#pragma unroll
  for (int nb = 0; nb < NB; ++nb) acc[nb] = (f32x4){0.f, 0.f, 0.f, 0.f};
#pragma unroll
  for (int kb = 0; kb < 4; ++kb){
    // A cols kb*32 + q*8 + j  -> panel 2kb + (q>>1), offset (q&1)*8
    bf16x8 a = *(const bf16x8*)(apan + (size_t)(2 * kb + (q >> 1)) * PANEL
                                + (size_t)(m0 + n) * 16 + (q & 1) * 8);
    const u16* wbase = g_wp + wpoff + (kb * NB) * 512 + lane * 8;
#pragma unroll
    for (int nb = 0; nb < NB; ++nb){
      bf16x8 w = *(const bf16x8*)(wbase + nb * 512);
      acc[nb] = __builtin_amdgcn_mfma_f32_16x16x32_bf16(a, w, acc[nb], 0, 0, 0);
    }
  }
#pragma unroll
  for (int r = 0; r < 4; ++r){
    int node = m0 + q * 4 + r;
    float di = g_dinv[node];
#pragma unroll
    for (int nb = 0; nb < NB; ++nb)
      dst[(size_t)nb * PANEL + (size_t)node * 16 + n] = (u16)f2bf(acc[nb][r] * di);
  }
}

// ---- 3) merged dispatch: CSR scatter (0..2499) + GEMM layer 1 (2500..3124) ----
__global__ __launch_bounds__(256) void k_fillgemm(const int* __restrict__ ei){
  int bid = (int)blockIdx.x;
  if (bid < 2500){
    int strd = detect_estride(ei);
    int e = bid * 256 + (int)threadIdx.x;
    if (e < NE){
      int d = clampi(ei[(size_t)(NE + e) * strd], 0, NN - 1);
      int s = clampi(ei[(size_t)e * strd], 0, NN - 1);
      int pos = clampi(g_rowptr[d] + atomicAdd(&g_cur[d], 1), 0, NE - 1);
      g_csrc[pos] = s;
    }
  } else {
    gemm_body<128>(bid - 2500, WP_W1, g_ha, g_hb);
  }
}

// ---- 4) standalone GEMM (layers 2, 3) ----
template<int JOUT, bool DST2>
__global__ __launch_bounds__(256) void k_gemm(int wpoff){
  gemm_body<JOUT>((int)blockIdx.x, wpoff, g_ha, DST2 ? g_hb2 : g_hb);
}

#define ACC8(P) do { \
    a0 += blo((P).x); a1 += bhi((P).x); \
    a2 += blo((P).y); a3 += bhi((P).y); \
    a4 += blo((P).z); a5 += bhi((P).z); \
    a6 += blo((P).w); a7 += bhi((P).w); } while (0)

// ---- 5) XCD-sharded CSR aggregation ----
// shard = blockIdx%8 (round-robin XCD heuristic; perf-only). Shard x gathers
// ONLY from its 1.25MB panel -> per-XCD L2-resident. Instruction count equals
// the unsharded uint4 form (16x16B gathers/edge total). JIN=128: 2 lanes/node,
// out = g_ha panels (bf16). JIN=64: 1 lane/node, out = h3 (f32).
template<int JIN, bool SRC2, bool RELU, bool ZCLR>
__global__ __launch_bounds__(256, 4) void k_aggsh(int boff, float* __restrict__ h3out){
  const u16* __restrict__ srcb = SRC2 ? g_hb2 : g_hb;
  int tid = (int)threadIdx.x;
  if (ZCLR){
    int gt = (int)blockIdx.x * 256 + tid;
    if (gt < NN){ g_cnt[gt] = 0; g_cur[gt] = 0; }
  }
  int shard = (int)blockIdx.x & 7;
  int bs = (int)blockIdx.x >> 3;
  int wid, coff;
  const u16* sp;
  if (JIN == 128){
    wid = bs * 128 + (tid >> 1);             // 2 lanes/node
    sp = srcb + (size_t)shard * PANEL;
    coff = (tid & 1) * 8;
  } else {
    wid = bs * 256 + tid;                    // 1 lane/node
    sp = srcb + (size_t)(shard >> 1) * PANEL;
    coff = (shard & 1) * 8;
  }
  if (wid >= NN) return;
  float di = g_dinv[wid];
  int beg = g_rowptr[wid], end = g_rowptr[wid + 1];
  uint4 ps = *(const uint4*)(sp + (size_t)wid * 16 + coff);   // self term
  float a0 = 0.f, a1 = 0.f, a2 = 0.f, a3 = 0.f, a4 = 0.f, a5 = 0.f, a6 = 0.f, a7 = 0.f;
  for (int e = beg; e < end; e += 8){
    int s0, s1, s2, s3, s4, s5, s6, s7;
    {
      int last = end - 1;
#define LDS_IDX(T) clampi(g_csrc[(e + T < last) ? (e + T) : last], 0, NN - 1)
      s0 = LDS_IDX(0); s1 = LDS_IDX(1); s2 = LDS_IDX(2); s3 = LDS_IDX(3);
      s4 = LDS_IDX(4); s5 = LDS_IDX(5); s6 = LDS_IDX(6); s7 = LDS_IDX(7);
#undef LDS_IDX
    }
    uint4 p0 = *(const uint4*)(sp + (size_t)s0 * 16 + coff);
    uint4 p1 = *(const uint4*)(sp + (size_t)s1 * 16 + coff);
    uint4 p2 = *(const uint4*)(sp + (size_t)s2 * 16 + coff);
    uint4 p3 = *(const uint4*)(sp + (size_t)s3 * 16 + coff);
    uint4 p4 = *(const uint4*)(sp + (size_t)s4 * 16 + coff);
    uint4 p5 = *(const uint4*)(sp + (size_t)s5 * 16 + coff);
    uint4 p6 = *(const uint4*)(sp + (size_t)s6 * 16 + coff);
    uint4 p7 = *(const uint4*)(sp + (size_t)s7 * 16 + coff);
    int nv = end - e;                        // valid count (>=1)
    ACC8(p0);
    if (nv > 1) ACC8(p1);
    if (nv > 2) ACC8(p2);
    if (nv > 3) ACC8(p3);
    if (nv > 4) ACC8(p4);
    if (nv > 5) ACC8(p5);
    if (nv > 6) ACC8(p6);
    if (nv > 7) ACC8(p7);
  }
  ACC8(ps);                                  // + h'[i] (self loop)
  int bb = boff + ((JIN == 128) ? (shard * 16 + coff) : (shard * 8));
  a0 = a0 * di + g_wf[bb];
  a1 = a1 * di + g_wf[bb + 1];
  a2 = a2 * di + g_wf[bb + 2];
  a3 = a3 * di + g_wf[bb + 3];
  a4 = a4 * di + g_wf[bb + 4];
  a5 = a5 * di + g_wf[bb + 5];
  a6 = a6 * di + g_wf[bb + 6];
  a7 = a7 * di + g_wf[bb + 7];
  if (RELU){
    a0 = fmaxf(a0, 0.f); a1 = fmaxf(a1, 0.f); a2 = fmaxf(a2, 0.f); a3 = fmaxf(a3, 0.f);
    a4 = fmaxf(a4, 0.f); a5 = fmaxf(a5, 0.f); a6 = fmaxf(a6, 0.f); a7 = fmaxf(a7, 0.f);
  }
  if (JIN == 128){
    uint4 o;
    o.x = f2bf(a0) | (f2bf(a1) << 16);
    o.y = f2bf(a2) | (f2bf(a3) << 16);
    o.z = f2bf(a4) | (f2bf(a5) << 16);
    o.w = f2bf(a6) | (f2bf(a7) << 16);
    *(uint4*)(g_ha + (size_t)shard * PANEL + (size_t)wid * 16 + coff) = o;
  } else {
    *(float4*)(h3out + (size_t)wid * 64 + shard * 8)     = make_float4(a0, a1, a2, a3);
    *(float4*)(h3out + (size_t)wid * 64 + shard * 8 + 4) = make_float4(a4, a5, a6, a7);
  }
}

// ---- 6) output head: out[wid] = h3row @ Wout + bout (bit-identical to R9) ----
__global__ __launch_bounds__(256) void k_head(const float* __restrict__ h3,
                                              float* __restrict__ outp){
  int gt = (int)blockIdx.x * 256 + (int)threadIdx.x;
  int wid = gt >> 3;
  int lane = (int)threadIdx.x & 7;
  if (wid >= NN) return;
  int cc = lane * 8;
  float4 v0 = *(const float4*)(h3 + (size_t)wid * 64 + cc);
  float4 v1 = *(const float4*)(h3 + (size_t)wid * 64 + cc + 4);
  float a0 = v0.x, a1 = v0.y, a2 = v0.z, a3 = v0.w;
  float a4 = v1.x, a5 = v1.y, a6 = v1.z, a7 = v1.w;
  float o0 = a0 * g_wf[OFF_WO + (cc + 0) * 2] + a1 * g_wf[OFF_WO + (cc + 1) * 2]
           + a2 * g_wf[OFF_WO + (cc + 2) * 2] + a3 * g_wf[OFF_WO + (cc + 3) * 2]
           + a4 * g_wf[OFF_WO + (cc + 4) * 2] + a5 * g_wf[OFF_WO + (cc + 5) * 2]
           + a6 * g_wf[OFF_WO + (cc + 6) * 2] + a7 * g_wf[OFF_WO + (cc + 7) * 2];
  float o1 = a0 * g_wf[OFF_WO + (cc + 0) * 2 + 1] + a1 * g_wf[OFF_WO + (cc + 1) * 2 + 1]
           + a2 * g_wf[OFF_WO + (cc + 2) * 2 + 1] + a3 * g_wf[OFF_WO + (cc + 3) * 2 + 1]
           + a4 * g_wf[OFF_WO + (cc + 4) * 2 + 1] + a5 * g_wf[OFF_WO + (cc + 5) * 2 + 1]
           + a6 * g_wf[OFF_WO + (cc + 6) * 2 + 1] + a7 * g_wf[OFF_WO + (cc + 7) * 2 + 1];
#pragma unroll
  for (int m = 1; m < 8; m <<= 1){
    o0 += __shfl_xor(o0, m, 64);
    o1 += __shfl_xor(o1, m, 64);
  }
  if (lane == 0){
    *(float2*)(outp + (size_t)wid * 2) =
      make_float2(o0 + g_wf[OFF_BO], o1 + g_wf[OFF_BO + 1]);
  }
}

extern "C" void kernel_launch(void* const* d_in, const int* in_sizes, int n_in,
                              void* d_out, int out_size, void* d_ws, size_t ws_size,
                              hipStream_t stream){
  const int* ei = (const int*)d_in[1];
  float* out = (float*)d_out;                    // [N,2] then [N,64], f32
  float* h3  = out + (size_t)NN * 2;

  k_prep<<<2662, 256, 0, stream>>>(d_in[0], ei, d_in[2], d_in[3], d_in[4], d_in[5],
                                   d_in[6], d_in[7], d_in[8], d_in[9]);
  k_scan1<<<40, 1024, 0, stream>>>();
  k_scan3<<<40, 1024, 0, stream>>>();
  k_fillgemm<<<3125, 256, 0, stream>>>(ei);                                   // fill | gemm1

  k_aggsh<128, false, true,  true ><<<2504, 256, 0, stream>>>(OFF_B1, nullptr); // agg1: g_hb -> g_ha
  k_gemm<128, true ><<<625, 256, 0, stream>>>(WP_W2);                           // gemm2: g_ha -> g_hb2
  k_aggsh<128, true,  true,  false><<<2504, 256, 0, stream>>>(OFF_B2, nullptr); // agg2: g_hb2 -> g_ha
  k_gemm<64,  false><<<625, 256, 0, stream>>>(WP_W3);                           // gemm3: g_ha -> g_hb
  k_aggsh<64,  false, false, false><<<1256, 256, 0, stream>>>(OFF_B3, h3);      // agg3: g_hb -> h3
  k_head<<<1250, 256, 0, stream>>>(h3, out);                                    // logits
}

// Round 13
// 229.754 us; speedup vs baseline: 1.1648x; 1.1648x over previous
//
#include <hip/hip_runtime.h>
#include <hip/hip_bf16.h>

#define NN 40000
#define NE 640000

typedef unsigned int u32;
typedef unsigned short u16;
typedef __attribute__((ext_vector_type(8))) short bf16x8;
typedef __attribute__((ext_vector_type(4))) float f32x4;

// ---------------- static device scratch (direct symbol use; no d_ws) -------
__device__ float g_wf[512];                  // biases + Wout + bout (f32)
__device__ u16   g_wp[40960];                // bf16 W1/W2/W3 in MFMA B-fragment layout
__device__ int   g_cnt[NN];                  // zero at load; re-zeroed by agggemm1 for next iter
__device__ int   g_cur[NN];                  // zero at load; re-zeroed by agggemm1 for next iter
__device__ int   g_rowptr[NN + 1];
__device__ float g_dinv[NN];
__device__ int   g_csrc[NE];
__device__ int   g_bsum[64];
__device__ u16   g_ha[(size_t)NN * 128];     // agg1/agg2 output (bf16 rows)
__device__ u16   g_hb[(size_t)NN * 128];     // ping: gemm1 out / gemm3 out (64 cols)
__device__ u16   g_hb2[(size_t)NN * 128];    // pong: gemm2 out

// g_wf offsets
#define OFF_B1 0
#define OFF_B2 128
#define OFF_B3 256
#define OFF_WO 320
#define OFF_BO 448
// g_wp offsets
#define WP_W1 0
#define WP_W2 16384
#define WP_W3 32768

__device__ __forceinline__ float b2f(u16 v){ return __uint_as_float(((u32)v) << 16); }
__device__ __forceinline__ float blo(u32 u){ return __uint_as_float(u << 16); }
__device__ __forceinline__ float bhi(u32 u){ return __uint_as_float(u & 0xffff0000u); }
__device__ __forceinline__ u32 f2bf(float f){
  u32 u = __float_as_uint(f);
  return (u + 0x7fffu + ((u >> 16) & 1u)) >> 16;   // RNE
}
__device__ __forceinline__ int clampi(int v, int lo, int hi){ return v < lo ? lo : (v > hi ? hi : v); }
__device__ __forceinline__ u16 ldbf(const void* p, int idx, int f32){
  return f32 ? (u16)f2bf(((const float*)p)[idx]) : ((const u16*)p)[idx];
}
__device__ __forceinline__ float ldf(const void* p, int idx, int f32){
  return f32 ? ((const float*)p)[idx] : b2f(((const u16*)p)[idx]);
}

// ---- per-block dtype self-detection (64 fixed samples, wave ballot) ----
__device__ __forceinline__ int detect_xf32(const u16* __restrict__ xf){
  int i = ((int)threadIdx.x & 63) * 64;
  u16 v = xf[2 * i];
  int e = (v >> 7) & 0xff;
  int pass = (v == 0 || (e >= 100 && e <= 140)) ? 1 : 0;
  return (__popcll(__ballot(pass)) < 32) ? 1 : 0;        // few bf16-like -> f32
}
__device__ __forceinline__ int detect_estride(const int* __restrict__ ei){
  int i = ((int)threadIdx.x & 63) * 64;
  int pass = (ei[2 * i + 1] == 0) ? 1 : 0;               // int64 high words are 0
  return (__popcll(__ballot(pass)) >= 32) ? 2 : 1;
}

// ---- 1) fused preamble: in-degree count | packw | f32 table ----
// x is NOT converted here anymore: gemm1 reads it directly from the input
// buffer (same f2bf rounding -> bit-identical g_hb). prep's T<640000 range is
// count-only (5MB dst read + atomics). g_cnt/g_cur zero at module load,
// re-zeroed by agggemm1 each pass.
__global__ __launch_bounds__(256) void k_prep(const void* xin, const int* __restrict__ ei,
                                              const void* w1, const void* b1,
                                              const void* w2, const void* b2, const void* w3,
                                              const void* b3, const void* wo, const void* bo){
  int xf32 = detect_xf32((const u16*)xin);
  int strd = detect_estride(ei);
  int T = (int)blockIdx.x * 256 + (int)threadIdx.x;
  if (T < 640000){
    int d = clampi(ei[(size_t)(NE + T) * strd], 0, NN - 1);
    atomicAdd(&g_cnt[d], 1);
  } else if (T < 680960){
    int local = T - 640000;
    int J, dstbase, l; const void* src;
    if (local < 16384){ J = 128; src = w1; dstbase = WP_W1; l = local; }
    else if (local < 32768){ J = 128; src = w2; dstbase = WP_W2; l = local - 16384; }
    else { J = 64; src = w3; dstbase = WP_W3; l = local - 32768; }
    int chunk = l >> 9, within = l & 511;
    int nbw = J / 16;
    int kb = chunk / nbw, nb = chunk % nbw;
    int lane = within >> 3, j = within & 7;
    int q = lane >> 4, n = lane & 15;
    int k = kb * 32 + q * 8 + j;
    int col = nb * 16 + n;
    g_wp[dstbase + l] = ldbf(src, k * J + col, xf32);
  } else if (T < 681410){
    int l = T - 680960;                      // 0..449
    if (l < 128)      g_wf[OFF_B1 + l] = ldf(b1, l, xf32);
    else if (l < 256) g_wf[OFF_B2 + l - 128] = ldf(b2, l - 128, xf32);
    else if (l < 320) g_wf[OFF_B3 + l - 256] = ldf(b3, l - 256, xf32);
    else if (l < 448) g_wf[OFF_WO + l - 320] = ldf(wo, l - 320, xf32);
    else              g_wf[OFF_BO + l - 448] = ldf(bo, l - 448, xf32);
  }
}

// ---- 2a) block-level scan (40 blocks x 1024): local exclusive + block sums ----
__global__ __launch_bounds__(1024) void k_scan1(){
  int t = (int)threadIdx.x;
  int b = (int)blockIdx.x;
  int i = b * 1024 + t;
  int v = (i < NN) ? g_cnt[i] : 0;
  int lane = t & 63, wv = t >> 6;
  int x = v;
#pragma unroll
  for (int ofs = 1; ofs < 64; ofs <<= 1){
    int y = __shfl_up(x, ofs, 64);
    if (lane >= ofs) x += y;
  }
  __shared__ int wsum[16];
  if (lane == 63) wsum[wv] = x;
  __syncthreads();
  if (t < 16){
    int s = wsum[t];
#pragma unroll
    for (int ofs = 1; ofs < 16; ofs <<= 1){
      int y = __shfl_up(s, ofs, 64);
      if (t >= ofs) s += y;
    }
    wsum[t] = s;
  }
  __syncthreads();
  int pre = (wv == 0) ? 0 : wsum[wv - 1];
  int incl = x + pre;
  if (i < NN){
    g_rowptr[i] = incl - v;
    g_dinv[i] = rsqrtf((float)(v + 1));
  }
  if (t == 1023) g_bsum[b] = incl;
}

// ---- 2b) add block offsets ----
__global__ __launch_bounds__(1024) void k_scan3(){
  __shared__ int pre;
  int t = (int)threadIdx.x;
  if (t < 64){
    int v = (t < 40) ? g_bsum[t] : 0;
    int s = v;
#pragma unroll
    for (int ofs = 1; ofs < 64; ofs <<= 1){
      int y = __shfl_up(s, ofs, 64);
      if (t >= ofs) s += y;
    }
    if (t == (int)blockIdx.x) pre = s - v;               // exclusive prefix for this block
    if (blockIdx.x == 0 && t == 39) g_rowptr[NN] = s;    // grand total
  }
  __syncthreads();
  int i = (int)blockIdx.x * 1024 + t;
  if (i < NN) g_rowptr[i] += pre;
}

// ---- 3) merged dispatch: CSR scatter (0..2499) + GEMM layer 1 (2500..3124) ----
// gemm1 reads x DIRECTLY from the input buffer (f32 cvt in-register via the
// same f2bf RNE, or raw bf16) -> g_hb, rows pre-scaled by dinv.
__global__ __launch_bounds__(256) void k_fillgemm(const int* __restrict__ ei,
                                                  const void* __restrict__ xin){
  int bid = (int)blockIdx.x;
  if (bid < 2500){
    int strd = detect_estride(ei);
    int e = bid * 256 + (int)threadIdx.x;
    if (e < NE){
      int d = clampi(ei[(size_t)(NE + e) * strd], 0, NN - 1);
      int s = clampi(ei[(size_t)e * strd], 0, NN - 1);
      int pos = clampi(g_rowptr[d] + atomicAdd(&g_cur[d], 1), 0, NE - 1);
      g_csrc[pos] = s;
    }
  } else {
    int xf32 = detect_xf32((const u16*)xin);
    constexpr int J = 128;
    constexpr int NB = J / 16;
    int tid = (int)threadIdx.x;
    int wave = tid >> 6, lane = tid & 63;
    int q = lane >> 4, n = lane & 15;
    int m0 = (bid - 2500) * 64 + wave * 16;
    f32x4 acc[NB];
#pragma unroll
    for (int nb = 0; nb < NB; ++nb) acc[nb] = (f32x4){0.f, 0.f, 0.f, 0.f};
#pragma unroll
    for (int kb = 0; kb < 4; ++kb){
      bf16x8 a;
      if (xf32){
        const float* xr = (const float*)xin + (size_t)(m0 + n) * 128 + q * 8 + kb * 32;
        float4 f0 = *(const float4*)(xr);
        float4 f1 = *(const float4*)(xr + 4);
        a[0] = (short)f2bf(f0.x); a[1] = (short)f2bf(f0.y);
        a[2] = (short)f2bf(f0.z); a[3] = (short)f2bf(f0.w);
        a[4] = (short)f2bf(f1.x); a[5] = (short)f2bf(f1.y);
        a[6] = (short)f2bf(f1.z); a[7] = (short)f2bf(f1.w);
      } else {
        a = *(const bf16x8*)((const u16*)xin + (size_t)(m0 + n) * 128 + q * 8 + kb * 32);
      }
      const u16* wbase = g_wp + WP_W1 + (kb * NB) * 512 + lane * 8;
#pragma unroll
      for (int nb = 0; nb < NB; ++nb){
        bf16x8 w = *(const bf16x8*)(wbase + nb * 512);
        acc[nb] = __builtin_amdgcn_mfma_f32_16x16x32_bf16(a, w, acc[nb], 0, 0, 0);
      }
    }
    u16* crow = g_hb + (size_t)(m0 + q * 4) * J + n;
#pragma unroll
    for (int r = 0; r < 4; ++r){
      float di = g_dinv[m0 + q * 4 + r];
#pragma unroll
      for (int nb = 0; nb < NB; ++nb)
        crow[(size_t)r * J + nb * 16] = (u16)f2bf(acc[nb][r] * di);
    }
  }
}

#define ACC8(P) do { \
    a0 += blo((P).x); a1 += bhi((P).x); \
    a2 += blo((P).y); a3 += bhi((P).y); \
    a4 += blo((P).z); a5 += bhi((P).z); \
    a6 += blo((P).w); a7 += bhi((P).w); } while (0)

// ---- 4) fused agg(layer i) + gemm(layer i+1): one block = 16 node rows ----
// (R9 structure, verbatim: best-measured at 229.5us.)
// SWAP=false: src=g_hb,  dst=g_hb2 (layers 1->2)
// SWAP=true : src=g_hb2, dst=g_hb  (layers 2->3)
template<int JOUT, bool SWAP, bool ZCLR>
__global__ __launch_bounds__(256, 4) void k_agggemm(int boff, int wpoff){
  constexpr int LSTRIDE = 136;               // u16 units; 272B padded row
  __shared__ u16 tile[16 * LSTRIDE];
  const u16* __restrict__ src = SWAP ? g_hb2 : g_hb;
  u16* __restrict__ dst = SWAP ? g_hb : g_hb2;
  int tid = (int)threadIdx.x;
  int gt = (int)blockIdx.x * 256 + tid;
  if (ZCLR){ if (gt < NN){ g_cnt[gt] = 0; g_cur[gt] = 0; } }
  int wid = gt >> 4;                         // node row (16 lanes/row); 2500*16 = NN exact
  int rt = tid >> 4;                         // row within tile 0..15
  int lane = tid & 15;
  int cc = lane * 8;
  float di = g_dinv[wid];
  int beg = g_rowptr[wid], end = g_rowptr[wid + 1];
  uint4 ps = *(const uint4*)(src + (size_t)wid * 128 + cc);   // self term
  float a0 = 0.f, a1 = 0.f, a2 = 0.f, a3 = 0.f, a4 = 0.f, a5 = 0.f, a6 = 0.f, a7 = 0.f;
  for (int e = beg; e < end; e += 8){
    int s0, s1, s2, s3, s4, s5, s6, s7;
    {
      int last = end - 1;
#define LDS_IDX(T) clampi(g_csrc[(e + T < last) ? (e + T) : last], 0, NN - 1)
      s0 = LDS_IDX(0); s1 = LDS_IDX(1); s2 = LDS_IDX(2); s3 = LDS_IDX(3);
      s4 = LDS_IDX(4); s5 = LDS_IDX(5); s6 = LDS_IDX(6); s7 = LDS_IDX(7);
#undef LDS_IDX
    }
    uint4 p0 = *(const uint4*)(src + (size_t)s0 * 128 + cc);
    uint4 p1 = *(const uint4*)(src + (size_t)s1 * 128 + cc);
    uint4 p2 = *(const uint4*)(src + (size_t)s2 * 128 + cc);
    uint4 p3 = *(const uint4*)(src + (size_t)s3 * 128 + cc);
    uint4 p4 = *(const uint4*)(src + (size_t)s4 * 128 + cc);
    uint4 p5 = *(const uint4*)(src + (size_t)s5 * 128 + cc);
    uint4 p6 = *(const uint4*)(src + (size_t)s6 * 128 + cc);
    uint4 p7 = *(const uint4*)(src + (size_t)s7 * 128 + cc);
    int nv = end - e;
    ACC8(p0);
    if (nv > 1) ACC8(p1);
    if (nv > 2) ACC8(p2);
    if (nv > 3) ACC8(p3);
    if (nv > 4) ACC8(p4);
    if (nv > 5) ACC8(p5);
    if (nv > 6) ACC8(p6);
    if (nv > 7) ACC8(p7);
  }
  ACC8(ps);
  a0 = a0 * di + g_wf[boff + cc];
  a1 = a1 * di + g_wf[boff + cc + 1];
  a2 = a2 * di + g_wf[boff + cc + 2];
  a3 = a3 * di + g_wf[boff + cc + 3];
  a4 = a4 * di + g_wf[boff + cc + 4];
  a5 = a5 * di + g_wf[boff + cc + 5];
  a6 = a6 * di + g_wf[boff + cc + 6];
  a7 = a7 * di + g_wf[boff + cc + 7];
  a0 = fmaxf(a0, 0.f); a1 = fmaxf(a1, 0.f); a2 = fmaxf(a2, 0.f); a3 = fmaxf(a3, 0.f);
  a4 = fmaxf(a4, 0.f); a5 = fmaxf(a5, 0.f); a6 = fmaxf(a6, 0.f); a7 = fmaxf(a7, 0.f);
  {
    uint4 o;
    o.x = f2bf(a0) | (f2bf(a1) << 16);
    o.y = f2bf(a2) | (f2bf(a3) << 16);
    o.z = f2bf(a4) | (f2bf(a5) << 16);
    o.w = f2bf(a6) | (f2bf(a7) << 16);
    *(uint4*)&tile[rt * LSTRIDE + cc] = o;
  }
  __syncthreads();
  // ---- gemm: 16 rows x 128 @ W[128 x JOUT] -> dst, rows scaled by dinv ----
  constexpr int NBF = JOUT / 16;             // total col-blocks (8 or 4)
  constexpr int NBW = NBF / 4;               // col-blocks per wave (2 or 1)
  int wave = tid >> 6, l64 = tid & 63;
  int q = l64 >> 4, n = l64 & 15;
  f32x4 acc[NBW];
#pragma unroll
  for (int j = 0; j < NBW; ++j) acc[j] = (f32x4){0.f, 0.f, 0.f, 0.f};
#pragma unroll
  for (int kb = 0; kb < 4; ++kb){
    bf16x8 a = *(const bf16x8*)&tile[n * LSTRIDE + q * 8 + kb * 32];
#pragma unroll
    for (int j = 0; j < NBW; ++j){
      int nb = wave * NBW + j;
      bf16x8 w = *(const bf16x8*)(g_wp + wpoff + (kb * NBF + nb) * 512 + l64 * 8);
      acc[j] = __builtin_amdgcn_mfma_f32_16x16x32_bf16(a, w, acc[j], 0, 0, 0);
    }
  }
  int m0 = (int)blockIdx.x * 16;
#pragma unroll
  for (int r = 0; r < 4; ++r){
    float dr = g_dinv[m0 + q * 4 + r];
#pragma unroll
    for (int j = 0; j < NBW; ++j){
      int nb = wave * NBW + j;
      dst[(size_t)(m0 + q * 4 + r) * JOUT + nb * 16 + n] = (u16)f2bf(acc[j][r] * dr);
    }
  }
}

// ---- 5) final CSR aggregation (layer 3, J=64 in) + fused output head ----
template<int J, bool RELU>
__global__ __launch_bounds__(256, 4) void k_agg(int boff, float* __restrict__ h3, float* __restrict__ outp){
  constexpr int LPR = J / 8;                 // lanes per row
  int gt = (int)blockIdx.x * 256 + (int)threadIdx.x;
  int wid = gt / LPR;
  int lane = (int)threadIdx.x & (LPR - 1);
  if (wid >= NN) return;
  int cc = lane * 8;
  const u16* __restrict__ hb = g_hb;
  float di = g_dinv[wid];
  int beg = g_rowptr[wid], end = g_rowptr[wid + 1];
  uint4 ps = *(const uint4*)(hb + (size_t)wid * J + cc);
  float a0 = 0.f, a1 = 0.f, a2 = 0.f, a3 = 0.f, a4 = 0.f, a5 = 0.f, a6 = 0.f, a7 = 0.f;
  for (int e = beg; e < end; e += 8){
    int s0, s1, s2, s3, s4, s5, s6, s7;
    {
      int last = end - 1;
#define LDS_IDX(T) clampi(g_csrc[(e + T < last) ? (e + T) : last], 0, NN - 1)
      s0 = LDS_IDX(0); s1 = LDS_IDX(1); s2 = LDS_IDX(2); s3 = LDS_IDX(3);
      s4 = LDS_IDX(4); s5 = LDS_IDX(5); s6 = LDS_IDX(6); s7 = LDS_IDX(7);
#undef LDS_IDX
    }
    uint4 p0 = *(const uint4*)(hb + (size_t)s0 * J + cc);
    uint4 p1 = *(const uint4*)(hb + (size_t)s1 * J + cc);
    uint4 p2 = *(const uint4*)(hb + (size_t)s2 * J + cc);
    uint4 p3 = *(const uint4*)(hb + (size_t)s3 * J + cc);
    uint4 p4 = *(const uint4*)(hb + (size_t)s4 * J + cc);
    uint4 p5 = *(const uint4*)(hb + (size_t)s5 * J + cc);
    uint4 p6 = *(const uint4*)(hb + (size_t)s6 * J + cc);
    uint4 p7 = *(const uint4*)(hb + (size_t)s7 * J + cc);
    int nv = end - e;
    ACC8(p0);
    if (nv > 1) ACC8(p1);
    if (nv > 2) ACC8(p2);
    if (nv > 3) ACC8(p3);
    if (nv > 4) ACC8(p4);
    if (nv > 5) ACC8(p5);
    if (nv > 6) ACC8(p6);
    if (nv > 7) ACC8(p7);
  }
  ACC8(ps);
  a0 = a0 * di + g_wf[boff + cc];
  a1 = a1 * di + g_wf[boff + cc + 1];
  a2 = a2 * di + g_wf[boff + cc + 2];
  a3 = a3 * di + g_wf[boff + cc + 3];
  a4 = a4 * di + g_wf[boff + cc + 4];
  a5 = a5 * di + g_wf[boff + cc + 5];
  a6 = a6 * di + g_wf[boff + cc + 6];
  a7 = a7 * di + g_wf[boff + cc + 7];
  if (RELU){
    a0 = fmaxf(a0, 0.f); a1 = fmaxf(a1, 0.f); a2 = fmaxf(a2, 0.f); a3 = fmaxf(a3, 0.f);
    a4 = fmaxf(a4, 0.f); a5 = fmaxf(a5, 0.f); a6 = fmaxf(a6, 0.f); a7 = fmaxf(a7, 0.f);
  }
  *(float4*)(h3 + (size_t)wid * 64 + cc)     = make_float4(a0, a1, a2, a3);
  *(float4*)(h3 + (size_t)wid * 64 + cc + 4) = make_float4(a4, a5, a6, a7);
  // fused output head: out[wid] = h3row @ Wout + bout, 8-lane shuffle reduce
  float o0 = a0 * g_wf[OFF_WO + (cc + 0) * 2] + a1 * g_wf[OFF_WO + (cc + 1) * 2]
           + a2 * g_wf[OFF_WO + (cc + 2) * 2] + a3 * g_wf[OFF_WO + (cc + 3) * 2]
           + a4 * g_wf[OFF_WO + (cc + 4) * 2] + a5 * g_wf[OFF_WO + (cc + 5) * 2]
           + a6 * g_wf[OFF_WO + (cc + 6) * 2] + a7 * g_wf[OFF_WO + (cc + 7) * 2];
  float o1 = a0 * g_wf[OFF_WO + (cc + 0) * 2 + 1] + a1 * g_wf[OFF_WO + (cc + 1) * 2 + 1]
           + a2 * g_wf[OFF_WO + (cc + 2) * 2 + 1] + a3 * g_wf[OFF_WO + (cc + 3) * 2 + 1]
           + a4 * g_wf[OFF_WO + (cc + 4) * 2 + 1] + a5 * g_wf[OFF_WO + (cc + 5) * 2 + 1]
           + a6 * g_wf[OFF_WO + (cc + 6) * 2 + 1] + a7 * g_wf[OFF_WO + (cc + 7) * 2 + 1];
#pragma unroll
  for (int m = 1; m < 8; m <<= 1){
    o0 += __shfl_xor(o0, m, 64);
    o1 += __shfl_xor(o1, m, 64);
  }
  if (lane == 0){
    *(float2*)(outp + (size_t)wid * 2) =
      make_float2(o0 + g_wf[OFF_BO], o1 + g_wf[OFF_BO + 1]);
  }
}

extern "C" void kernel_launch(void* const* d_in, const int* in_sizes, int n_in,
                              void* d_out, int out_size, void* d_ws, size_t ws_size,
                              hipStream_t stream){
  const int* ei = (const int*)d_in[1];
  float* out = (float*)d_out;                    // [N,2] then [N,64], f32
  float* h3  = out + (size_t)NN * 2;

  k_prep<<<2662, 256, 0, stream>>>(d_in[0], ei, d_in[2], d_in[3], d_in[4], d_in[5],
                                   d_in[6], d_in[7], d_in[8], d_in[9]);
  k_scan1<<<40, 1024, 0, stream>>>();
  k_scan3<<<40, 1024, 0, stream>>>();
  k_fillgemm<<<3125, 256, 0, stream>>>(ei, d_in[0]);                          // fill | gemm1(x direct)

  k_agggemm<128, false, true><<<2500, 256, 0, stream>>>(OFF_B1, WP_W2);       // agg1+gemm2: g_hb -> g_hb2
  k_agggemm<64, true, false><<<2500, 256, 0, stream>>>(OFF_B2, WP_W3);        // agg2+gemm3: g_hb2 -> g_hb
  k_agg<64, false><<<1250, 256, 0, stream>>>(OFF_B3, h3, out);                // agg3 + head
}

// Round 14
// 229.652 us; speedup vs baseline: 1.1653x; 1.0004x over previous
//
#include <hip/hip_runtime.h>
#include <hip/hip_bf16.h>

#define NN 40000
#define NE 640000

typedef unsigned int u32;
typedef unsigned short u16;
typedef __attribute__((ext_vector_type(8))) short bf16x8;
typedef __attribute__((ext_vector_type(4))) float f32x4;

// ---------------- static device scratch (direct symbol use; no d_ws) -------
__device__ float g_wf[512];                  // biases + Wout + bout (f32)
__device__ u16   g_wp[40960];                // bf16 W1/W2/W3 in MFMA B-fragment layout
__device__ int   g_cnt[NN];                  // zero at load; re-zeroed by agggemm1 for next iter
__device__ int   g_cur[NN];                  // zero at load; re-zeroed by agggemm1 for next iter
__device__ int   g_rowptr[NN + 1];
__device__ float g_dinv[NN];
__device__ int   g_csrc[NE];
__device__ int   g_bsum[64];
__device__ u16   g_ha[(size_t)NN * 128];     // agg1/agg2 output (bf16 rows)
__device__ u16   g_hb[(size_t)NN * 128];     // ping: gemm1 out / gemm3 out (64 cols)
__device__ u16   g_hb2[(size_t)NN * 128];    // pong: gemm2 out

// g_wf offsets
#define OFF_B1 0
#define OFF_B2 128
#define OFF_B3 256
#define OFF_WO 320
#define OFF_BO 448
// g_wp offsets
#define WP_W1 0
#define WP_W2 16384
#define WP_W3 32768

__device__ __forceinline__ float b2f(u16 v){ return __uint_as_float(((u32)v) << 16); }
__device__ __forceinline__ float blo(u32 u){ return __uint_as_float(u << 16); }
__device__ __forceinline__ float bhi(u32 u){ return __uint_as_float(u & 0xffff0000u); }
__device__ __forceinline__ u32 f2bf(float f){
  u32 u = __float_as_uint(f);
  return (u + 0x7fffu + ((u >> 16) & 1u)) >> 16;   // RNE
}
__device__ __forceinline__ int clampi(int v, int lo, int hi){ return v < lo ? lo : (v > hi ? hi : v); }
__device__ __forceinline__ u16 ldbf(const void* p, int idx, int f32){
  return f32 ? (u16)f2bf(((const float*)p)[idx]) : ((const u16*)p)[idx];
}
__device__ __forceinline__ float ldf(const void* p, int idx, int f32){
  return f32 ? ((const float*)p)[idx] : b2f(((const u16*)p)[idx]);
}

// ---- per-block dtype self-detection (64 fixed samples, wave ballot) ----
__device__ __forceinline__ int detect_xf32(const u16* __restrict__ xf){
  int i = ((int)threadIdx.x & 63) * 64;
  u16 v = xf[2 * i];
  int e = (v >> 7) & 0xff;
  int pass = (v == 0 || (e >= 100 && e <= 140)) ? 1 : 0;
  return (__popcll(__ballot(pass)) < 32) ? 1 : 0;        // few bf16-like -> f32
}
__device__ __forceinline__ int detect_estride(const int* __restrict__ ei){
  int i = ((int)threadIdx.x & 63) * 64;
  int pass = (ei[2 * i + 1] == 0) ? 1 : 0;               // int64 high words are 0
  return (__popcll(__ballot(pass)) >= 32) ? 2 : 1;
}

// ---- 1) fused preamble: in-degree count | packw | f32 table ----
// x is read directly by gemm1 (no conversion pass). g_cnt/g_cur zero at module
// load, re-zeroed by agggemm1 each pass.
__global__ __launch_bounds__(256) void k_prep(const void* xin, const int* __restrict__ ei,
                                              const void* w1, const void* b1,
                                              const void* w2, const void* b2, const void* w3,
                                              const void* b3, const void* wo, const void* bo){
  int xf32 = detect_xf32((const u16*)xin);
  int strd = detect_estride(ei);
  int T = (int)blockIdx.x * 256 + (int)threadIdx.x;
  if (T < 640000){
    int d = clampi(ei[(size_t)(NE + T) * strd], 0, NN - 1);
    atomicAdd(&g_cnt[d], 1);
  } else if (T < 680960){
    int local = T - 640000;
    int J, dstbase, l; const void* src;
    if (local < 16384){ J = 128; src = w1; dstbase = WP_W1; l = local; }
    else if (local < 32768){ J = 128; src = w2; dstbase = WP_W2; l = local - 16384; }
    else { J = 64; src = w3; dstbase = WP_W3; l = local - 32768; }
    int chunk = l >> 9, within = l & 511;
    int nbw = J / 16;
    int kb = chunk / nbw, nb = chunk % nbw;
    int lane = within >> 3, j = within & 7;
    int q = lane >> 4, n = lane & 15;
    int k = kb * 32 + q * 8 + j;
    int col = nb * 16 + n;
    g_wp[dstbase + l] = ldbf(src, k * J + col, xf32);
  } else if (T < 681410){
    int l = T - 680960;                      // 0..449
    if (l < 128)      g_wf[OFF_B1 + l] = ldf(b1, l, xf32);
    else if (l < 256) g_wf[OFF_B2 + l - 128] = ldf(b2, l - 128, xf32);
    else if (l < 320) g_wf[OFF_B3 + l - 256] = ldf(b3, l - 256, xf32);
    else if (l < 448) g_wf[OFF_WO + l - 320] = ldf(wo, l - 320, xf32);
    else              g_wf[OFF_BO + l - 448] = ldf(bo, l - 448, xf32);
  }
}

// ---- 2a) block-level scan (40 blocks x 1024): local exclusive + block sums ----
__global__ __launch_bounds__(1024) void k_scan1(){
  int t = (int)threadIdx.x;
  int b = (int)blockIdx.x;
  int i = b * 1024 + t;
  int v = (i < NN) ? g_cnt[i] : 0;
  int lane = t & 63, wv = t >> 6;
  int x = v;
#pragma unroll
  for (int ofs = 1; ofs < 64; ofs <<= 1){
    int y = __shfl_up(x, ofs, 64);
    if (lane >= ofs) x += y;
  }
  __shared__ int wsum[16];
  if (lane == 63) wsum[wv] = x;
  __syncthreads();
  if (t < 16){
    int s = wsum[t];
#pragma unroll
    for (int ofs = 1; ofs < 16; ofs <<= 1){
      int y = __shfl_up(s, ofs, 64);
      if (t >= ofs) s += y;
    }
    wsum[t] = s;
  }
  __syncthreads();
  int pre = (wv == 0) ? 0 : wsum[wv - 1];
  int incl = x + pre;
  if (i < NN){
    g_rowptr[i] = incl - v;
    g_dinv[i] = rsqrtf((float)(v + 1));
  }
  if (t == 1023) g_bsum[b] = incl;
}

// ---- 2b) add block offsets ----
__global__ __launch_bounds__(1024) void k_scan3(){
  __shared__ int pre;
  int t = (int)threadIdx.x;
  if (t < 64){
    int v = (t < 40) ? g_bsum[t] : 0;
    int s = v;
#pragma unroll
    for (int ofs = 1; ofs < 64; ofs <<= 1){
      int y = __shfl_up(s, ofs, 64);
      if (t >= ofs) s += y;
    }
    if (t == (int)blockIdx.x) pre = s - v;               // exclusive prefix for this block
    if (blockIdx.x == 0 && t == 39) g_rowptr[NN] = s;    // grand total
  }
  __syncthreads();
  int i = (int)blockIdx.x * 1024 + t;
  if (i < NN) g_rowptr[i] += pre;
}

// ---- 3) merged dispatch: dst-PARTITIONED CSR scatter (0..2503) + GEMM1 ----
// Partition p = bid&7 writes only dsts in [p*5000,(p+1)*5000): with the
// round-robin block->XCD map, each g_csrc window (320KB) + g_cur range is
// dirtied by ONE XCD's L2 -> sector writebacks coalesce (52MB -> ~13MB HBM
// write). Cost: 8x re-read of the 5MB dst column (streaming, L2/L3-absorbed).
// Intra-row CSR order changes (reassociation only). gemm1 (blocks 2504+)
// reads x directly from the input buffer (f2bf RNE in-register).
__global__ __launch_bounds__(256) void k_fillgemm(const int* __restrict__ ei,
                                                  const void* __restrict__ xin){
  int bid = (int)blockIdx.x;
  if (bid < 2504){
    int part = bid & 7;
    int chunk = bid >> 3;                    // 0..312
    int lo = part * 5000, hi = lo + 5000;
    int strd = detect_estride(ei);
    int tid = (int)threadIdx.x;
#pragma unroll
    for (int it = 0; it < 8; ++it){
      int e = chunk * 2048 + it * 256 + tid;
      if (e < NE){
        int d = clampi(ei[(size_t)(NE + e) * strd], 0, NN - 1);
        if (d >= lo && d < hi){
          int s = clampi(ei[(size_t)e * strd], 0, NN - 1);
          int pos = clampi(g_rowptr[d] + atomicAdd(&g_cur[d], 1), 0, NE - 1);
          g_csrc[pos] = s;
        }
      }
    }
  } else {
    int xf32 = detect_xf32((const u16*)xin);
    constexpr int J = 128;
    constexpr int NB = J / 16;
    int tid = (int)threadIdx.x;
    int wave = tid >> 6, lane = tid & 63;
    int q = lane >> 4, n = lane & 15;
    int m0 = (bid - 2504) * 64 + wave * 16;
    f32x4 acc[NB];
#pragma unroll
    for (int nb = 0; nb < NB; ++nb) acc[nb] = (f32x4){0.f, 0.f, 0.f, 0.f};
#pragma unroll
    for (int kb = 0; kb < 4; ++kb){
      bf16x8 a;
      if (xf32){
        const float* xr = (const float*)xin + (size_t)(m0 + n) * 128 + q * 8 + kb * 32;
        float4 f0 = *(const float4*)(xr);
        float4 f1 = *(const float4*)(xr + 4);
        a[0] = (short)f2bf(f0.x); a[1] = (short)f2bf(f0.y);
        a[2] = (short)f2bf(f0.z); a[3] = (short)f2bf(f0.w);
        a[4] = (short)f2bf(f1.x); a[5] = (short)f2bf(f1.y);
        a[6] = (short)f2bf(f1.z); a[7] = (short)f2bf(f1.w);
      } else {
        a = *(const bf16x8*)((const u16*)xin + (size_t)(m0 + n) * 128 + q * 8 + kb * 32);
      }
      const u16* wbase = g_wp + WP_W1 + (kb * NB) * 512 + lane * 8;
#pragma unroll
      for (int nb = 0; nb < NB; ++nb){
        bf16x8 w = *(const bf16x8*)(wbase + nb * 512);
        acc[nb] = __builtin_amdgcn_mfma_f32_16x16x32_bf16(a, w, acc[nb], 0, 0, 0);
      }
    }
    u16* crow = g_hb + (size_t)(m0 + q * 4) * J + n;
#pragma unroll
    for (int r = 0; r < 4; ++r){
      float di = g_dinv[m0 + q * 4 + r];
#pragma unroll
      for (int nb = 0; nb < NB; ++nb)
        crow[(size_t)r * J + nb * 16] = (u16)f2bf(acc[nb][r] * di);
    }
  }
}

#define ACC8(P) do { \
    a0 += blo((P).x); a1 += bhi((P).x); \
    a2 += blo((P).y); a3 += bhi((P).y); \
    a4 += blo((P).z); a5 += bhi((P).z); \
    a6 += blo((P).w); a7 += bhi((P).w); } while (0)

// ---- 4) fused agg(layer i) + gemm(layer i+1): one block = 16 node rows ----
// (R9 structure, verbatim: best-measured.)
// SWAP=false: src=g_hb,  dst=g_hb2 (layers 1->2)
// SWAP=true : src=g_hb2, dst=g_hb  (layers 2->3)
template<int JOUT, bool SWAP, bool ZCLR>
__global__ __launch_bounds__(256, 4) void k_agggemm(int boff, int wpoff){
  constexpr int LSTRIDE = 136;               // u16 units; 272B padded row
  __shared__ u16 tile[16 * LSTRIDE];
  const u16* __restrict__ src = SWAP ? g_hb2 : g_hb;
  u16* __restrict__ dst = SWAP ? g_hb : g_hb2;
  int tid = (int)threadIdx.x;
  int gt = (int)blockIdx.x * 256 + tid;
  if (ZCLR){ if (gt < NN){ g_cnt[gt] = 0; g_cur[gt] = 0; } }
  int wid = gt >> 4;                         // node row (16 lanes/row); 2500*16 = NN exact
  int rt = tid >> 4;                         // row within tile 0..15
  int lane = tid & 15;
  int cc = lane * 8;
  float di = g_dinv[wid];
  int beg = g_rowptr[wid], end = g_rowptr[wid + 1];
  uint4 ps = *(const uint4*)(src + (size_t)wid * 128 + cc);   // self term
  float a0 = 0.f, a1 = 0.f, a2 = 0.f, a3 = 0.f, a4 = 0.f, a5 = 0.f, a6 = 0.f, a7 = 0.f;
  for (int e = beg; e < end; e += 8){
    int s0, s1, s2, s3, s4, s5, s6, s7;
    {
      int last = end - 1;
#define LDS_IDX(T) clampi(g_csrc[(e + T < last) ? (e + T) : last], 0, NN - 1)
      s0 = LDS_IDX(0); s1 = LDS_IDX(1); s2 = LDS_IDX(2); s3 = LDS_IDX(3);
      s4 = LDS_IDX(4); s5 = LDS_IDX(5); s6 = LDS_IDX(6); s7 = LDS_IDX(7);
#undef LDS_IDX
    }
    uint4 p0 = *(const uint4*)(src + (size_t)s0 * 128 + cc);
    uint4 p1 = *(const uint4*)(src + (size_t)s1 * 128 + cc);
    uint4 p2 = *(const uint4*)(src + (size_t)s2 * 128 + cc);
    uint4 p3 = *(const uint4*)(src + (size_t)s3 * 128 + cc);
    uint4 p4 = *(const uint4*)(src + (size_t)s4 * 128 + cc);
    uint4 p5 = *(const uint4*)(src + (size_t)s5 * 128 + cc);
    uint4 p6 = *(const uint4*)(src + (size_t)s6 * 128 + cc);
    uint4 p7 = *(const uint4*)(src + (size_t)s7 * 128 + cc);
    int nv = end - e;
    ACC8(p0);
    if (nv > 1) ACC8(p1);
    if (nv > 2) ACC8(p2);
    if (nv > 3) ACC8(p3);
    if (nv > 4) ACC8(p4);
    if (nv > 5) ACC8(p5);
    if (nv > 6) ACC8(p6);
    if (nv > 7) ACC8(p7);
  }
  ACC8(ps);
  a0 = a0 * di + g_wf[boff + cc];
  a1 = a1 * di + g_wf[boff + cc + 1];
  a2 = a2 * di + g_wf[boff + cc + 2];
  a3 = a3 * di + g_wf[boff + cc + 3];
  a4 = a4 * di + g_wf[boff + cc + 4];
  a5 = a5 * di + g_wf[boff + cc + 5];
  a6 = a6 * di + g_wf[boff + cc + 6];
  a7 = a7 * di + g_wf[boff + cc + 7];
  a0 = fmaxf(a0, 0.f); a1 = fmaxf(a1, 0.f); a2 = fmaxf(a2, 0.f); a3 = fmaxf(a3, 0.f);
  a4 = fmaxf(a4, 0.f); a5 = fmaxf(a5, 0.f); a6 = fmaxf(a6, 0.f); a7 = fmaxf(a7, 0.f);
  {
    uint4 o;
    o.x = f2bf(a0) | (f2bf(a1) << 16);
    o.y = f2bf(a2) | (f2bf(a3) << 16);
    o.z = f2bf(a4) | (f2bf(a5) << 16);
    o.w = f2bf(a6) | (f2bf(a7) << 16);
    *(uint4*)&tile[rt * LSTRIDE + cc] = o;
  }
  __syncthreads();
  // ---- gemm: 16 rows x 128 @ W[128 x JOUT] -> dst, rows scaled by dinv ----
  constexpr int NBF = JOUT / 16;             // total col-blocks (8 or 4)
  constexpr int NBW = NBF / 4;               // col-blocks per wave (2 or 1)
  int wave = tid >> 6, l64 = tid & 63;
  int q = l64 >> 4, n = l64 & 15;
  f32x4 acc[NBW];
#pragma unroll
  for (int j = 0; j < NBW; ++j) acc[j] = (f32x4){0.f, 0.f, 0.f, 0.f};
#pragma unroll
  for (int kb = 0; kb < 4; ++kb){
    bf16x8 a = *(const bf16x8*)&tile[n * LSTRIDE + q * 8 + kb * 32];
#pragma unroll
    for (int j = 0; j < NBW; ++j){
      int nb = wave * NBW + j;
      bf16x8 w = *(const bf16x8*)(g_wp + wpoff + (kb * NBF + nb) * 512 + l64 * 8);
      acc[j] = __builtin_amdgcn_mfma_f32_16x16x32_bf16(a, w, acc[j], 0, 0, 0);
    }
  }
  int m0 = (int)blockIdx.x * 16;
#pragma unroll
  for (int r = 0; r < 4; ++r){
    float dr = g_dinv[m0 + q * 4 + r];
#pragma unroll
    for (int j = 0; j < NBW; ++j){
      int nb = wave * NBW + j;
      dst[(size_t)(m0 + q * 4 + r) * JOUT + nb * 16 + n] = (u16)f2bf(acc[j][r] * dr);
    }
  }
}

// ---- 5) final CSR aggregation (layer 3, J=64 in) + fused output head ----
template<int J, bool RELU>
__global__ __launch_bounds__(256, 4) void k_agg(int boff, float* __restrict__ h3, float* __restrict__ outp){
  constexpr int LPR = J / 8;                 // lanes per row
  int gt = (int)blockIdx.x * 256 + (int)threadIdx.x;
  int wid = gt / LPR;
  int lane = (int)threadIdx.x & (LPR - 1);
  if (wid >= NN) return;
  int cc = lane * 8;
  const u16* __restrict__ hb = g_hb;
  float di = g_dinv[wid];
  int beg = g_rowptr[wid], end = g_rowptr[wid + 1];
  uint4 ps = *(const uint4*)(hb + (size_t)wid * J + cc);
  float a0 = 0.f, a1 = 0.f, a2 = 0.f, a3 = 0.f, a4 = 0.f, a5 = 0.f, a6 = 0.f, a7 = 0.f;
  for (int e = beg; e < end; e += 8){
    int s0, s1, s2, s3, s4, s5, s6, s7;
    {
      int last = end - 1;
#define LDS_IDX(T) clampi(g_csrc[(e + T < last) ? (e + T) : last], 0, NN - 1)
      s0 = LDS_IDX(0); s1 = LDS_IDX(1); s2 = LDS_IDX(2); s3 = LDS_IDX(3);
      s4 = LDS_IDX(4); s5 = LDS_IDX(5); s6 = LDS_IDX(6); s7 = LDS_IDX(7);
#undef LDS_IDX
    }
    uint4 p0 = *(const uint4*)(hb + (size_t)s0 * J + cc);
    uint4 p1 = *(const uint4*)(hb + (size_t)s1 * J + cc);
    uint4 p2 = *(const uint4*)(hb + (size_t)s2 * J + cc);
    uint4 p3 = *(const uint4*)(hb + (size_t)s3 * J + cc);
    uint4 p4 = *(const uint4*)(hb + (size_t)s4 * J + cc);
    uint4 p5 = *(const uint4*)(hb + (size_t)s5 * J + cc);
    uint4 p6 = *(const uint4*)(hb + (size_t)s6 * J + cc);
    uint4 p7 = *(const uint4*)(hb + (size_t)s7 * J + cc);
    int nv = end - e;
    ACC8(p0);
    if (nv > 1) ACC8(p1);
    if (nv > 2) ACC8(p2);
    if (nv > 3) ACC8(p3);
    if (nv > 4) ACC8(p4);
    if (nv > 5) ACC8(p5);
    if (nv > 6) ACC8(p6);
    if (nv > 7) ACC8(p7);
  }
  ACC8(ps);
  a0 = a0 * di + g_wf[boff + cc];
  a1 = a1 * di + g_wf[boff + cc + 1];
  a2 = a2 * di + g_wf[boff + cc + 2];
  a3 = a3 * di + g_wf[boff + cc + 3];
  a4 = a4 * di + g_wf[boff + cc + 4];
  a5 = a5 * di + g_wf[boff + cc + 5];
  a6 = a6 * di + g_wf[boff + cc + 6];
  a7 = a7 * di + g_wf[boff + cc + 7];
  if (RELU){
    a0 = fmaxf(a0, 0.f); a1 = fmaxf(a1, 0.f); a2 = fmaxf(a2, 0.f); a3 = fmaxf(a3, 0.f);
    a4 = fmaxf(a4, 0.f); a5 = fmaxf(a5, 0.f); a6 = fmaxf(a6, 0.f); a7 = fmaxf(a7, 0.f);
  }
  *(float4*)(h3 + (size_t)wid * 64 + cc)     = make_float4(a0, a1, a2, a3);
  *(float4*)(h3 + (size_t)wid * 64 + cc + 4) = make_float4(a4, a5, a6, a7);
  // fused output head: out[wid] = h3row @ Wout + bout, 8-lane shuffle reduce
  float o0 = a0 * g_wf[OFF_WO + (cc + 0) * 2] + a1 * g_wf[OFF_WO + (cc + 1) * 2]
           + a2 * g_wf[OFF_WO + (cc + 2) * 2] + a3 * g_wf[OFF_WO + (cc + 3) * 2]
           + a4 * g_wf[OFF_WO + (cc + 4) * 2] + a5 * g_wf[OFF_WO + (cc + 5) * 2]
           + a6 * g_wf[OFF_WO + (cc + 6) * 2] + a7 * g_wf[OFF_WO + (cc + 7) * 2];
  float o1 = a0 * g_wf[OFF_WO + (cc + 0) * 2 + 1] + a1 * g_wf[OFF_WO + (cc + 1) * 2 + 1]
           + a2 * g_wf[OFF_WO + (cc + 2) * 2 + 1] + a3 * g_wf[OFF_WO + (cc + 3) * 2 + 1]
           + a4 * g_wf[OFF_WO + (cc + 4) * 2 + 1] + a5 * g_wf[OFF_WO + (cc + 5) * 2 + 1]
           + a6 * g_wf[OFF_WO + (cc + 6) * 2 + 1] + a7 * g_wf[OFF_WO + (cc + 7) * 2 + 1];
#pragma unroll
  for (int m = 1; m < 8; m <<= 1){
    o0 += __shfl_xor(o0, m, 64);
    o1 += __shfl_xor(o1, m, 64);
  }
  if (lane == 0){
    *(float2*)(outp + (size_t)wid * 2) =
      make_float2(o0 + g_wf[OFF_BO], o1 + g_wf[OFF_BO + 1]);
  }
}

extern "C" void kernel_launch(void* const* d_in, const int* in_sizes, int n_in,
                              void* d_out, int out_size, void* d_ws, size_t ws_size,
                              hipStream_t stream){
  const int* ei = (const int*)d_in[1];
  float* out = (float*)d_out;                    // [N,2] then [N,64], f32
  float* h3  = out + (size_t)NN * 2;

  k_prep<<<2662, 256, 0, stream>>>(d_in[0], ei, d_in[2], d_in[3], d_in[4], d_in[5],
                                   d_in[6], d_in[7], d_in[8], d_in[9]);
  k_scan1<<<40, 1024, 0, stream>>>();
  k_scan3<<<40, 1024, 0, stream>>>();
  k_fillgemm<<<3129, 256, 0, stream>>>(ei, d_in[0]);                          // part-fill | gemm1

  k_agggemm<128, false, true><<<2500, 256, 0, stream>>>(OFF_B1, WP_W2);       // agg1+gemm2: g_hb -> g_hb2
  k_agggemm<64, true, false><<<2500, 256, 0, stream>>>(OFF_B2, WP_W3);        // agg2+gemm3: g_hb2 -> g_hb
  k_agg<64, false><<<1250, 256, 0, stream>>>(OFF_B3, h3, out);                // agg3 + head
}

// Round 15
// 209.411 us; speedup vs baseline: 1.2779x; 1.0967x over previous
//
#include <hip/hip_runtime.h>
#include <hip/hip_bf16.h>

#define NN 40000
#define NE 640000

typedef unsigned int u32;
typedef unsigned short u16;
typedef __attribute__((ext_vector_type(8))) short bf16x8;
typedef __attribute__((ext_vector_type(4))) float f32x4;

// ---------------- static device scratch (direct symbol use; no d_ws) -------
__device__ float g_wf[512];                  // biases + Wout + bout (f32)
__device__ u16   g_wp[40960];                // bf16 W1/W2/W3 in MFMA B-fragment layout
__device__ int   g_cnt[NN];                  // zero at load; re-zeroed by agggemm1 for next iter
__device__ int   g_rowptr[NN + 1];
__device__ float g_dinv[NN];
__device__ int   g_csrc[NE];
__device__ int   g_pos[NE];                  // per-edge slot within dst row (from prep's atomic)
__device__ int   g_bsum[64];
__device__ u16   g_ha[(size_t)NN * 128];     // agg1/agg2 output (bf16 rows)
__device__ u16   g_hb[(size_t)NN * 128];     // ping: gemm1 out / gemm3 out (64 cols)
__device__ u16   g_hb2[(size_t)NN * 128];    // pong: gemm2 out

// g_wf offsets
#define OFF_B1 0
#define OFF_B2 128
#define OFF_B3 256
#define OFF_WO 320
#define OFF_BO 448
// g_wp offsets
#define WP_W1 0
#define WP_W2 16384
#define WP_W3 32768

__device__ __forceinline__ float b2f(u16 v){ return __uint_as_float(((u32)v) << 16); }
__device__ __forceinline__ float blo(u32 u){ return __uint_as_float(u << 16); }
__device__ __forceinline__ float bhi(u32 u){ return __uint_as_float(u & 0xffff0000u); }
__device__ __forceinline__ u32 f2bf(float f){
  u32 u = __float_as_uint(f);
  return (u + 0x7fffu + ((u >> 16) & 1u)) >> 16;   // RNE
}
__device__ __forceinline__ int clampi(int v, int lo, int hi){ return v < lo ? lo : (v > hi ? hi : v); }
__device__ __forceinline__ u16 ldbf(const void* p, int idx, int f32){
  return f32 ? (u16)f2bf(((const float*)p)[idx]) : ((const u16*)p)[idx];
}
__device__ __forceinline__ float ldf(const void* p, int idx, int f32){
  return f32 ? ((const float*)p)[idx] : b2f(((const u16*)p)[idx]);
}

// ---- per-block dtype self-detection (64 fixed samples, wave ballot) ----
__device__ __forceinline__ int detect_xf32(const u16* __restrict__ xf){
  int i = ((int)threadIdx.x & 63) * 64;
  u16 v = xf[2 * i];
  int e = (v >> 7) & 0xff;
  int pass = (v == 0 || (e >= 100 && e <= 140)) ? 1 : 0;
  return (__popcll(__ballot(pass)) < 32) ? 1 : 0;        // few bf16-like -> f32
}
__device__ __forceinline__ int detect_estride(const int* __restrict__ ei){
  int i = ((int)threadIdx.x & 63) * 64;
  int pass = (ei[2 * i + 1] == 0) ? 1 : 0;               // int64 high words are 0
  return (__popcll(__ballot(pass)) >= 32) ? 2 : 1;
}

// ---- 1) fused preamble: in-degree count + SLOT ASSIGNMENT | packw | table ----
// The count atomic's return value is the edge's unique slot within its dst
// row -> stored in g_pos so the fill needs NO atomics (it was transaction-
// rate-bound on them). g_cnt zero at module load, re-zeroed by agggemm1.
__global__ __launch_bounds__(256) void k_prep(const void* xin, const int* __restrict__ ei,
                                              const void* w1, const void* b1,
                                              const void* w2, const void* b2, const void* w3,
                                              const void* b3, const void* wo, const void* bo){
  int xf32 = detect_xf32((const u16*)xin);
  int strd = detect_estride(ei);
  int T = (int)blockIdx.x * 256 + (int)threadIdx.x;
  if (T < 640000){
    int d = clampi(ei[(size_t)(NE + T) * strd], 0, NN - 1);
    g_pos[T] = atomicAdd(&g_cnt[d], 1);
  } else if (T < 680960){
    int local = T - 640000;
    int J, dstbase, l; const void* src;
    if (local < 16384){ J = 128; src = w1; dstbase = WP_W1; l = local; }
    else if (local < 32768){ J = 128; src = w2; dstbase = WP_W2; l = local - 16384; }
    else { J = 64; src = w3; dstbase = WP_W3; l = local - 32768; }
    int chunk = l >> 9, within = l & 511;
    int nbw = J / 16;
    int kb = chunk / nbw, nb = chunk % nbw;
    int lane = within >> 3, j = within & 7;
    int q = lane >> 4, n = lane & 15;
    int k = kb * 32 + q * 8 + j;
    int col = nb * 16 + n;
    g_wp[dstbase + l] = ldbf(src, k * J + col, xf32);
  } else if (T < 681410){
    int l = T - 680960;                      // 0..449
    if (l < 128)      g_wf[OFF_B1 + l] = ldf(b1, l, xf32);
    else if (l < 256) g_wf[OFF_B2 + l - 128] = ldf(b2, l - 128, xf32);
    else if (l < 320) g_wf[OFF_B3 + l - 256] = ldf(b3, l - 256, xf32);
    else if (l < 448) g_wf[OFF_WO + l - 320] = ldf(wo, l - 320, xf32);
    else              g_wf[OFF_BO + l - 448] = ldf(bo, l - 448, xf32);
  }
}

// ---- 2a) block-level scan (40 blocks x 1024): local exclusive + block sums ----
__global__ __launch_bounds__(1024) void k_scan1(){
  int t = (int)threadIdx.x;
  int b = (int)blockIdx.x;
  int i = b * 1024 + t;
  int v = (i < NN) ? g_cnt[i] : 0;
  int lane = t & 63, wv = t >> 6;
  int x = v;
#pragma unroll
  for (int ofs = 1; ofs < 64; ofs <<= 1){
    int y = __shfl_up(x, ofs, 64);
    if (lane >= ofs) x += y;
  }
  __shared__ int wsum[16];
  if (lane == 63) wsum[wv] = x;
  __syncthreads();
  if (t < 16){
    int s = wsum[t];
#pragma unroll
    for (int ofs = 1; ofs < 16; ofs <<= 1){
      int y = __shfl_up(s, ofs, 64);
      if (t >= ofs) s += y;
    }
    wsum[t] = s;
  }
  __syncthreads();
  int pre = (wv == 0) ? 0 : wsum[wv - 1];
  int incl = x + pre;
  if (i < NN){
    g_rowptr[i] = incl - v;
    g_dinv[i] = rsqrtf((float)(v + 1));
  }
  if (t == 1023) g_bsum[b] = incl;
}

// ---- 2b) add block offsets ----
__global__ __launch_bounds__(1024) void k_scan3(){
  __shared__ int pre;
  int t = (int)threadIdx.x;
  if (t < 64){
    int v = (t < 40) ? g_bsum[t] : 0;
    int s = v;
#pragma unroll
    for (int ofs = 1; ofs < 64; ofs <<= 1){
      int y = __shfl_up(s, ofs, 64);
      if (t >= ofs) s += y;
    }
    if (t == (int)blockIdx.x) pre = s - v;               // exclusive prefix for this block
    if (blockIdx.x == 0 && t == 39) g_rowptr[NN] = s;    // grand total
  }
  __syncthreads();
  int i = (int)blockIdx.x * 1024 + t;
  if (i < NN) g_rowptr[i] += pre;
}

// ---- 3) merged dispatch: ATOMIC-FREE CSR scatter (0..2499) + GEMM1 ----
// pos = rowptr[d] + g_pos[e] (slot assigned in prep) -> pure read/write, no
// atomic transactions in this dispatch. gemm1 (blocks 2500+) reads x directly
// from the input buffer (f2bf RNE in-register).
__global__ __launch_bounds__(256) void k_fillgemm(const int* __restrict__ ei,
                                                  const void* __restrict__ xin){
  int bid = (int)blockIdx.x;
  if (bid < 2500){
    int strd = detect_estride(ei);
    int e = bid * 256 + (int)threadIdx.x;
    if (e < NE){
      int d = clampi(ei[(size_t)(NE + e) * strd], 0, NN - 1);
      int s = clampi(ei[(size_t)e * strd], 0, NN - 1);
      int pos = clampi(g_rowptr[d] + g_pos[e], 0, NE - 1);
      g_csrc[pos] = s;
    }
  } else {
    int xf32 = detect_xf32((const u16*)xin);
    constexpr int J = 128;
    constexpr int NB = J / 16;
    int tid = (int)threadIdx.x;
    int wave = tid >> 6, lane = tid & 63;
    int q = lane >> 4, n = lane & 15;
    int m0 = (bid - 2500) * 64 + wave * 16;
    f32x4 acc[NB];
#pragma unroll
    for (int nb = 0; nb < NB; ++nb) acc[nb] = (f32x4){0.f, 0.f, 0.f, 0.f};
#pragma unroll
    for (int kb = 0; kb < 4; ++kb){
      bf16x8 a;
      if (xf32){
        const float* xr = (const float*)xin + (size_t)(m0 + n) * 128 + q * 8 + kb * 32;
        float4 f0 = *(const float4*)(xr);
        float4 f1 = *(const float4*)(xr + 4);
        a[0] = (short)f2bf(f0.x); a[1] = (short)f2bf(f0.y);
        a[2] = (short)f2bf(f0.z); a[3] = (short)f2bf(f0.w);
        a[4] = (short)f2bf(f1.x); a[5] = (short)f2bf(f1.y);
        a[6] = (short)f2bf(f1.z); a[7] = (short)f2bf(f1.w);
      } else {
        a = *(const bf16x8*)((const u16*)xin + (size_t)(m0 + n) * 128 + q * 8 + kb * 32);
      }
      const u16* wbase = g_wp + WP_W1 + (kb * NB) * 512 + lane * 8;
#pragma unroll
      for (int nb = 0; nb < NB; ++nb){
        bf16x8 w = *(const bf16x8*)(wbase + nb * 512);
        acc[nb] = __builtin_amdgcn_mfma_f32_16x16x32_bf16(a, w, acc[nb], 0, 0, 0);
      }
    }
    u16* crow = g_hb + (size_t)(m0 + q * 4) * J + n;
#pragma unroll
    for (int r = 0; r < 4; ++r){
      float di = g_dinv[m0 + q * 4 + r];
#pragma unroll
      for (int nb = 0; nb < NB; ++nb)
        crow[(size_t)r * J + nb * 16] = (u16)f2bf(acc[nb][r] * di);
    }
  }
}

#define ACC8(P) do { \
    a0 += blo((P).x); a1 += bhi((P).x); \
    a2 += blo((P).y); a3 += bhi((P).y); \
    a4 += blo((P).z); a5 += bhi((P).z); \
    a6 += blo((P).w); a7 += bhi((P).w); } while (0)

// ---- 4) fused agg(layer i) + gemm(layer i+1): one block = 16 node rows ----
// (R9 structure, verbatim: best-measured.)
// SWAP=false: src=g_hb,  dst=g_hb2 (layers 1->2)
// SWAP=true : src=g_hb2, dst=g_hb  (layers 2->3)
template<int JOUT, bool SWAP, bool ZCLR>
__global__ __launch_bounds__(256, 4) void k_agggemm(int boff, int wpoff){
  constexpr int LSTRIDE = 136;               // u16 units; 272B padded row
  __shared__ u16 tile[16 * LSTRIDE];
  const u16* __restrict__ src = SWAP ? g_hb2 : g_hb;
  u16* __restrict__ dst = SWAP ? g_hb : g_hb2;
  int tid = (int)threadIdx.x;
  int gt = (int)blockIdx.x * 256 + tid;
  if (ZCLR){ if (gt < NN){ g_cnt[gt] = 0; } }
  int wid = gt >> 4;                         // node row (16 lanes/row); 2500*16 = NN exact
  int rt = tid >> 4;                         // row within tile 0..15
  int lane = tid & 15;
  int cc = lane * 8;
  float di = g_dinv[wid];
  int beg = g_rowptr[wid], end = g_rowptr[wid + 1];
  uint4 ps = *(const uint4*)(src + (size_t)wid * 128 + cc);   // self term
  float a0 = 0.f, a1 = 0.f, a2 = 0.f, a3 = 0.f, a4 = 0.f, a5 = 0.f, a6 = 0.f, a7 = 0.f;
  for (int e = beg; e < end; e += 8){
    int s0, s1, s2, s3, s4, s5, s6, s7;
    {
      int last = end - 1;
#define LDS_IDX(T) clampi(g_csrc[(e + T < last) ? (e + T) : last], 0, NN - 1)
      s0 = LDS_IDX(0); s1 = LDS_IDX(1); s2 = LDS_IDX(2); s3 = LDS_IDX(3);
      s4 = LDS_IDX(4); s5 = LDS_IDX(5); s6 = LDS_IDX(6); s7 = LDS_IDX(7);
#undef LDS_IDX
    }
    uint4 p0 = *(const uint4*)(src + (size_t)s0 * 128 + cc);
    uint4 p1 = *(const uint4*)(src + (size_t)s1 * 128 + cc);
    uint4 p2 = *(const uint4*)(src + (size_t)s2 * 128 + cc);
    uint4 p3 = *(const uint4*)(src + (size_t)s3 * 128 + cc);
    uint4 p4 = *(const uint4*)(src + (size_t)s4 * 128 + cc);
    uint4 p5 = *(const uint4*)(src + (size_t)s5 * 128 + cc);
    uint4 p6 = *(const uint4*)(src + (size_t)s6 * 128 + cc);
    uint4 p7 = *(const uint4*)(src + (size_t)s7 * 128 + cc);
    int nv = end - e;
    ACC8(p0);
    if (nv > 1) ACC8(p1);
    if (nv > 2) ACC8(p2);
    if (nv > 3) ACC8(p3);
    if (nv > 4) ACC8(p4);
    if (nv > 5) ACC8(p5);
    if (nv > 6) ACC8(p6);
    if (nv > 7) ACC8(p7);
  }
  ACC8(ps);
  a0 = a0 * di + g_wf[boff + cc];
  a1 = a1 * di + g_wf[boff + cc + 1];
  a2 = a2 * di + g_wf[boff + cc + 2];
  a3 = a3 * di + g_wf[boff + cc + 3];
  a4 = a4 * di + g_wf[boff + cc + 4];
  a5 = a5 * di + g_wf[boff + cc + 5];
  a6 = a6 * di + g_wf[boff + cc + 6];
  a7 = a7 * di + g_wf[boff + cc + 7];
  a0 = fmaxf(a0, 0.f); a1 = fmaxf(a1, 0.f); a2 = fmaxf(a2, 0.f); a3 = fmaxf(a3, 0.f);
  a4 = fmaxf(a4, 0.f); a5 = fmaxf(a5, 0.f); a6 = fmaxf(a6, 0.f); a7 = fmaxf(a7, 0.f);
  {
    uint4 o;
    o.x = f2bf(a0) | (f2bf(a1) << 16);
    o.y = f2bf(a2) | (f2bf(a3) << 16);
    o.z = f2bf(a4) | (f2bf(a5) << 16);
    o.w = f2bf(a6) | (f2bf(a7) << 16);
    *(uint4*)&tile[rt * LSTRIDE + cc] = o;
  }
  __syncthreads();
  // ---- gemm: 16 rows x 128 @ W[128 x JOUT] -> dst, rows scaled by dinv ----
  constexpr int NBF = JOUT / 16;             // total col-blocks (8 or 4)
  constexpr int NBW = NBF / 4;               // col-blocks per wave (2 or 1)
  int wave = tid >> 6, l64 = tid & 63;
  int q = l64 >> 4, n = l64 & 15;
  f32x4 acc[NBW];
#pragma unroll
  for (int j = 0; j < NBW; ++j) acc[j] = (f32x4){0.f, 0.f, 0.f, 0.f};
#pragma unroll
  for (int kb = 0; kb < 4; ++kb){
    bf16x8 a = *(const bf16x8*)&tile[n * LSTRIDE + q * 8 + kb * 32];
#pragma unroll
    for (int j = 0; j < NBW; ++j){
      int nb = wave * NBW + j;
      bf16x8 w = *(const bf16x8*)(g_wp + wpoff + (kb * NBF + nb) * 512 + l64 * 8);
      acc[j] = __builtin_amdgcn_mfma_f32_16x16x32_bf16(a, w, acc[j], 0, 0, 0);
    }
  }
  int m0 = (int)blockIdx.x * 16;
#pragma unroll
  for (int r = 0; r < 4; ++r){
    float dr = g_dinv[m0 + q * 4 + r];
#pragma unroll
    for (int j = 0; j < NBW; ++j){
      int nb = wave * NBW + j;
      dst[(size_t)(m0 + q * 4 + r) * JOUT + nb * 16 + n] = (u16)f2bf(acc[j][r] * dr);
    }
  }
}

// ---- 5) final CSR aggregation (layer 3, J=64 in) + fused output head ----
template<int J, bool RELU>
__global__ __launch_bounds__(256, 4) void k_agg(int boff, float* __restrict__ h3, float* __restrict__ outp){
  constexpr int LPR = J / 8;                 // lanes per row
  int gt = (int)blockIdx.x * 256 + (int)threadIdx.x;
  int wid = gt / LPR;
  int lane = (int)threadIdx.x & (LPR - 1);
  if (wid >= NN) return;
  int cc = lane * 8;
  const u16* __restrict__ hb = g_hb;
  float di = g_dinv[wid];
  int beg = g_rowptr[wid], end = g_rowptr[wid + 1];
  uint4 ps = *(const uint4*)(hb + (size_t)wid * J + cc);
  float a0 = 0.f, a1 = 0.f, a2 = 0.f, a3 = 0.f, a4 = 0.f, a5 = 0.f, a6 = 0.f, a7 = 0.f;
  for (int e = beg; e < end; e += 8){
    int s0, s1, s2, s3, s4, s5, s6, s7;
    {
      int last = end - 1;
#define LDS_IDX(T) clampi(g_csrc[(e + T < last) ? (e + T) : last], 0, NN - 1)
      s0 = LDS_IDX(0); s1 = LDS_IDX(1); s2 = LDS_IDX(2); s3 = LDS_IDX(3);
      s4 = LDS_IDX(4); s5 = LDS_IDX(5); s6 = LDS_IDX(6); s7 = LDS_IDX(7);
#undef LDS_IDX
    }
    uint4 p0 = *(const uint4*)(hb + (size_t)s0 * J + cc);
    uint4 p1 = *(const uint4*)(hb + (size_t)s1 * J + cc);
    uint4 p2 = *(const uint4*)(hb + (size_t)s2 * J + cc);
    uint4 p3 = *(const uint4*)(hb + (size_t)s3 * J + cc);
    uint4 p4 = *(const uint4*)(hb + (size_t)s4 * J + cc);
    uint4 p5 = *(const uint4*)(hb + (size_t)s5 * J + cc);
    uint4 p6 = *(const uint4*)(hb + (size_t)s6 * J + cc);
    uint4 p7 = *(const uint4*)(hb + (size_t)s7 * J + cc);
    int nv = end - e;
    ACC8(p0);
    if (nv > 1) ACC8(p1);
    if (nv > 2) ACC8(p2);
    if (nv > 3) ACC8(p3);
    if (nv > 4) ACC8(p4);
    if (nv > 5) ACC8(p5);
    if (nv > 6) ACC8(p6);
    if (nv > 7) ACC8(p7);
  }
  ACC8(ps);
  a0 = a0 * di + g_wf[boff + cc];
  a1 = a1 * di + g_wf[boff + cc + 1];
  a2 = a2 * di + g_wf[boff + cc + 2];
  a3 = a3 * di + g_wf[boff + cc + 3];
  a4 = a4 * di + g_wf[boff + cc + 4];
  a5 = a5 * di + g_wf[boff + cc + 5];
  a6 = a6 * di + g_wf[boff + cc + 6];
  a7 = a7 * di + g_wf[boff + cc + 7];
  if (RELU){
    a0 = fmaxf(a0, 0.f); a1 = fmaxf(a1, 0.f); a2 = fmaxf(a2, 0.f); a3 = fmaxf(a3, 0.f);
    a4 = fmaxf(a4, 0.f); a5 = fmaxf(a5, 0.f); a6 = fmaxf(a6, 0.f); a7 = fmaxf(a7, 0.f);
  }
  *(float4*)(h3 + (size_t)wid * 64 + cc)     = make_float4(a0, a1, a2, a3);
  *(float4*)(h3 + (size_t)wid * 64 + cc + 4) = make_float4(a4, a5, a6, a7);
  // fused output head: out[wid] = h3row @ Wout + bout, 8-lane shuffle reduce
  float o0 = a0 * g_wf[OFF_WO + (cc + 0) * 2] + a1 * g_wf[OFF_WO + (cc + 1) * 2]
           + a2 * g_wf[OFF_WO + (cc + 2) * 2] + a3 * g_wf[OFF_WO + (cc + 3) * 2]
           + a4 * g_wf[OFF_WO + (cc + 4) * 2] + a5 * g_wf[OFF_WO + (cc + 5) * 2]
           + a6 * g_wf[OFF_WO + (cc + 6) * 2] + a7 * g_wf[OFF_WO + (cc + 7) * 2];
  float o1 = a0 * g_wf[OFF_WO + (cc + 0) * 2 + 1] + a1 * g_wf[OFF_WO + (cc + 1) * 2 + 1]
           + a2 * g_wf[OFF_WO + (cc + 2) * 2 + 1] + a3 * g_wf[OFF_WO + (cc + 3) * 2 + 1]
           + a4 * g_wf[OFF_WO + (cc + 4) * 2 + 1] + a5 * g_wf[OFF_WO + (cc + 5) * 2 + 1]
           + a6 * g_wf[OFF_WO + (cc + 6) * 2 + 1] + a7 * g_wf[OFF_WO + (cc + 7) * 2 + 1];
#pragma unroll
  for (int m = 1; m < 8; m <<= 1){
    o0 += __shfl_xor(o0, m, 64);
    o1 += __shfl_xor(o1, m, 64);
  }
  if (lane == 0){
    *(float2*)(outp + (size_t)wid * 2) =
      make_float2(o0 + g_wf[OFF_BO], o1 + g_wf[OFF_BO + 1]);
  }
}

extern "C" void kernel_launch(void* const* d_in, const int* in_sizes, int n_in,
                              void* d_out, int out_size, void* d_ws, size_t ws_size,
                              hipStream_t stream){
  const int* ei = (const int*)d_in[1];
  float* out = (float*)d_out;                    // [N,2] then [N,64], f32
  float* h3  = out + (size_t)NN * 2;

  k_prep<<<2662, 256, 0, stream>>>(d_in[0], ei, d_in[2], d_in[3], d_in[4], d_in[5],
                                   d_in[6], d_in[7], d_in[8], d_in[9]);
  k_scan1<<<40, 1024, 0, stream>>>();
  k_scan3<<<40, 1024, 0, stream>>>();
  k_fillgemm<<<3125, 256, 0, stream>>>(ei, d_in[0]);                          // atomic-free fill | gemm1

  k_agggemm<128, false, true><<<2500, 256, 0, stream>>>(OFF_B1, WP_W2);       // agg1+gemm2: g_hb -> g_hb2
  k_agggemm<64, true, false><<<2500, 256, 0, stream>>>(OFF_B2, WP_W3);        // agg2+gemm3: g_hb2 -> g_hb
  k_agg<64, false><<<1250, 256, 0, stream>>>(OFF_B3, h3, out);                // agg3 + head
}